// Round 1
// baseline (362.741 us; speedup 1.0000x reference)
//
#include <hip/hip_runtime.h>

#define FV 128
#define NCLIN 38
#define NPIX 36
#define BATCH 1024
#define HID 512
#define COMB 4992   // 39*128

// ws layout (floats):
//   wc       [0,        16384)    W_self + W_msg/37
//   wi       [16384,    32768)    W_self + W_msg/39
//   t_clin   [32768,   163840)    (S_img/37)@W_msg + b_g   per (b,f)
//   t_img    [163840,  294912)    (S_clin/39)@W_msg + b_g  per (b,f)
//   combined [294912, 5406720)    (1024 x 4992)
//   z0       [5406720, 5931008)   partial z, K-half 0
//   z1       [5931008, 6455296)   partial z, K-half 1
#define WS_WC   0
#define WS_WI   16384
#define WS_TC   32768
#define WS_TI   163840
#define WS_COMB 294912
#define WS_Z0   5406720
#define WS_Z1   5931008

__global__ __launch_bounds__(128) void k_prep(
    const float* __restrict__ clin, const float* __restrict__ img,
    const float* __restrict__ wself, const float* __restrict__ wmsg,
    const float* __restrict__ bg, float* __restrict__ ws)
{
    const int b = blockIdx.x;
    const int f = threadIdx.x;
    if (b >= BATCH) {
        // weight prep: one row per block
        const int r = b - BATCH;
        const int idx = r * 128 + f;
        const float wm = wmsg[idx];
        const float s  = wself[idx];
        ws[WS_WC + idx] = s + wm * (1.0f / 37.0f);
        ws[WS_WI + idx] = s + wm * (1.0f / 39.0f);
        return;
    }
    __shared__ float lc[128];  // S_clin/39  (feeds image nodes)
    __shared__ float li[128];  // S_img/37   (feeds clinical nodes)
    float sc = 0.f, si = 0.f;
    const float* xc = clin + (size_t)b * NCLIN * FV + f;
#pragma unroll
    for (int n = 0; n < NCLIN; ++n) sc += xc[n * FV];
    const float* xi = img + (size_t)b * NPIX * FV + f;
#pragma unroll
    for (int n = 0; n < NPIX; ++n) si += xi[n * FV];
    lc[f] = sc * (1.0f / 39.0f);
    li[f] = si * (1.0f / 37.0f);
    __syncthreads();
    const float bgv = bg[f];
    float tc = bgv, ti = bgv;
#pragma unroll 4
    for (int k = 0; k < 128; ++k) {
        const float wm = wmsg[k * 128 + f];
        tc += li[k] * wm;   // clinical rows get (S_img/37)@W_msg
        ti += lc[k] * wm;   // image rows get (S_clin/39)@W_msg
    }
    ws[WS_TC + b * 128 + f] = tc;
    ws[WS_TI + b * 128 + f] = ti;
}

// One block per (batch, node-type). h = relu(x @ W + t); clinical h -> combined
// rows, image h -> mean (gap) -> last 128 of combined row.
__global__ __launch_bounds__(256) void k_nodes(
    const float* __restrict__ clin, const float* __restrict__ img,
    float* __restrict__ ws)
{
    const int b     = blockIdx.x;
    const int phase = blockIdx.y;            // 0 clinical, 1 image
    const int NN    = phase ? NPIX : NCLIN;
    const float* x  = phase ? (img + (size_t)b * NPIX * FV)
                            : (clin + (size_t)b * NCLIN * FV);
    const float* W  = ws + (phase ? WS_WI : WS_WC);
    const float* tv = ws + (phase ? WS_TI : WS_TC) + b * 128;
    float* combined = ws + WS_COMB + (size_t)b * COMB;

    __shared__ float xl[NCLIN * 128];   // 19 KB (max node count)
    __shared__ float Wl[128 * 64];      // 32 KB (one f-half of W)
    __shared__ float gred[16 * 64];     // 4 KB  (gap cross-group reduce)

    const int t = threadIdx.x;
    // stage x (float4)
    const int cnt4 = NN * 32;
    for (int i = t; i < cnt4; i += 256)
        ((float4*)xl)[i] = ((const float4*)x)[i];

    const int g  = t >> 4;          // node group 0..15
    const int f0 = (t & 15) * 4;    // feature quad within half

    for (int fhalf = 0; fhalf < 2; ++fhalf) {
        __syncthreads();   // protect Wl/gred reuse + xl availability
        // stage W half: Wl[k][fq] = W[k][fhalf*64 + fq]
        {
            const int fq4  = (t & 15) * 4;
            const int krow = t >> 4;
#pragma unroll
            for (int j = 0; j < 8; ++j) {
                const int k = krow + 16 * j;
                const float4 v = *(const float4*)&W[k * 128 + fhalf * 64 + fq4];
                *(float4*)&Wl[k * 64 + fq4] = v;
            }
        }
        __syncthreads();

        float acc[3][4] = {};
        for (int k0 = 0; k0 < 128; k0 += 4) {
            float4 wv0 = *(const float4*)&Wl[(k0 + 0) * 64 + f0];
            float4 wv1 = *(const float4*)&Wl[(k0 + 1) * 64 + f0];
            float4 wv2 = *(const float4*)&Wl[(k0 + 2) * 64 + f0];
            float4 wv3 = *(const float4*)&Wl[(k0 + 3) * 64 + f0];
#pragma unroll
            for (int i = 0; i < 3; ++i) {
                const int n = g + 16 * i;
                if (n < NN) {
                    const float4 xv = *(const float4*)&xl[n * 128 + k0];
                    acc[i][0] += xv.x * wv0.x + xv.y * wv1.x + xv.z * wv2.x + xv.w * wv3.x;
                    acc[i][1] += xv.x * wv0.y + xv.y * wv1.y + xv.z * wv2.y + xv.w * wv3.y;
                    acc[i][2] += xv.x * wv0.z + xv.y * wv1.z + xv.z * wv2.z + xv.w * wv3.z;
                    acc[i][3] += xv.x * wv0.w + xv.y * wv1.w + xv.z * wv2.w + xv.w * wv3.w;
                }
            }
        }

        const float t0 = tv[fhalf * 64 + f0 + 0];
        const float t1 = tv[fhalf * 64 + f0 + 1];
        const float t2 = tv[fhalf * 64 + f0 + 2];
        const float t3 = tv[fhalf * 64 + f0 + 3];

        if (phase == 0) {
#pragma unroll
            for (int i = 0; i < 3; ++i) {
                const int n = g + 16 * i;
                if (n < NN) {
                    float4 r;
                    r.x = fmaxf(acc[i][0] + t0, 0.f);
                    r.y = fmaxf(acc[i][1] + t1, 0.f);
                    r.z = fmaxf(acc[i][2] + t2, 0.f);
                    r.w = fmaxf(acc[i][3] + t3, 0.f);
                    *(float4*)&combined[n * 128 + fhalf * 64 + f0] = r;
                }
            }
        } else {
            float gp0 = 0.f, gp1 = 0.f, gp2 = 0.f, gp3 = 0.f;
#pragma unroll
            for (int i = 0; i < 3; ++i) {
                const int n = g + 16 * i;
                if (n < NN) {
                    gp0 += fmaxf(acc[i][0] + t0, 0.f);
                    gp1 += fmaxf(acc[i][1] + t1, 0.f);
                    gp2 += fmaxf(acc[i][2] + t2, 0.f);
                    gp3 += fmaxf(acc[i][3] + t3, 0.f);
                }
            }
            float4 gv = { gp0, gp1, gp2, gp3 };
            *(float4*)&gred[g * 64 + f0] = gv;
            __syncthreads();
            if (t < 64) {
                float s = 0.f;
#pragma unroll
                for (int gg = 0; gg < 16; ++gg) s += gred[gg * 64 + t];
                combined[NCLIN * 128 + fhalf * 64 + t] = s * (1.0f / 36.0f);
            }
        }
    }
}

// z_partial[ks] = combined[:, ksK:(ks+1)K] @ W1[ksK:(ks+1)K, :]
// TM=TN=64, BK=32, micro 4x4, grid (16, 8, 2)
__global__ __launch_bounds__(256) void k_gemm(
    const float* __restrict__ W1, float* __restrict__ ws)
{
    const float* A = ws + WS_COMB;                       // (1024, 4992)
    const int bm = blockIdx.x;                           // 0..15
    const int bn = blockIdx.y;                           // 0..7
    const int ks = blockIdx.z;                           // 0..1
    float* Z = ws + WS_Z0 + (size_t)ks * (BATCH * HID);

    __shared__ float As[32 * 68];   // [k][m], stride 68 pad
    __shared__ float Bs[32 * 64];   // [k][n]

    const int t = threadIdx.x;
    const int arow = t >> 5;        // 0..7  (m row for A staging)
    const int acol = t & 31;        // k for A staging
    const int bcol = t & 63;        // n for B staging
    const int brow = t >> 6;        // 0..3 k for B staging
    const int m0 = (t >> 4) * 4;
    const int n0 = (t & 15) * 4;
    const int kbase = ks * 2496;

    float acc[4][4] = {};

    for (int kb = 0; kb < 2496; kb += 32) {
        __syncthreads();
#pragma unroll
        for (int rr = 0; rr < 8; ++rr) {
            const int r = arow + rr * 8;
            As[acol * 68 + r] =
                A[(size_t)(bm * 64 + r) * COMB + kbase + kb + acol];
        }
#pragma unroll
        for (int kk2 = 0; kk2 < 8; ++kk2) {
            const int kk = brow + kk2 * 4;
            Bs[kk * 64 + bcol] =
                W1[(size_t)(kbase + kb + kk) * HID + bn * 64 + bcol];
        }
        __syncthreads();
#pragma unroll
        for (int k = 0; k < 32; ++k) {
            const float4 a4 = *(const float4*)&As[k * 68 + m0];
            const float4 b4 = *(const float4*)&Bs[k * 64 + n0];
            acc[0][0] += a4.x * b4.x; acc[0][1] += a4.x * b4.y;
            acc[0][2] += a4.x * b4.z; acc[0][3] += a4.x * b4.w;
            acc[1][0] += a4.y * b4.x; acc[1][1] += a4.y * b4.y;
            acc[1][2] += a4.y * b4.z; acc[1][3] += a4.y * b4.w;
            acc[2][0] += a4.z * b4.x; acc[2][1] += a4.z * b4.y;
            acc[2][2] += a4.z * b4.z; acc[2][3] += a4.z * b4.w;
            acc[3][0] += a4.w * b4.x; acc[3][1] += a4.w * b4.y;
            acc[3][2] += a4.w * b4.z; acc[3][3] += a4.w * b4.w;
        }
    }
#pragma unroll
    for (int im = 0; im < 4; ++im) {
        float4 r = { acc[im][0], acc[im][1], acc[im][2], acc[im][3] };
        *(float4*)&Z[(size_t)(bm * 64 + m0 + im) * HID + bn * 64 + n0] = r;
    }
}

__global__ __launch_bounds__(64) void k_out(
    const float* __restrict__ b1, const float* __restrict__ W2,
    const float* __restrict__ b2, const float* __restrict__ ws,
    float* __restrict__ out)
{
    const int b = blockIdx.x;
    const int l = threadIdx.x;
    const float* z0 = ws + WS_Z0 + (size_t)b * HID;
    const float* z1 = ws + WS_Z1 + (size_t)b * HID;
    float s = 0.f;
#pragma unroll
    for (int j = 0; j < 8; ++j) {
        const int h = l + j * 64;
        float z = z0[h] + z1[h] + b1[h];
        z = fmaxf(z, 0.f);
        s += z * W2[h];
    }
#pragma unroll
    for (int off = 32; off > 0; off >>= 1) s += __shfl_down(s, off);
    if (l == 0) out[b] = s + b2[0];
}

extern "C" void kernel_launch(void* const* d_in, const int* in_sizes, int n_in,
                              void* d_out, int out_size, void* d_ws, size_t ws_size,
                              hipStream_t stream) {
    const float* clin  = (const float*)d_in[0];  // (1024, 38, 128)
    const float* img   = (const float*)d_in[1];  // (1024, 36, 128)
    const float* wself = (const float*)d_in[2];  // (128, 128)
    const float* wmsg  = (const float*)d_in[3];  // (128, 128)
    const float* bg    = (const float*)d_in[4];  // (128,)
    const float* W1    = (const float*)d_in[5];  // (4992, 512)
    const float* b1    = (const float*)d_in[6];  // (512,)
    const float* W2    = (const float*)d_in[7];  // (512, 1)
    const float* b2    = (const float*)d_in[8];  // (1,)
    // d_in[9] edge_index: structure is fixed/known — unused.
    float* ws  = (float*)d_ws;
    float* out = (float*)d_out;

    k_prep<<<dim3(BATCH + 128), 128, 0, stream>>>(clin, img, wself, wmsg, bg, ws);
    k_nodes<<<dim3(BATCH, 2), 256, 0, stream>>>(clin, img, ws);
    k_gemm<<<dim3(16, 8, 2), 256, 0, stream>>>(W1, ws);
    k_out<<<dim3(BATCH), 64, 0, stream>>>(b1, W2, b2, ws, out);
}

// Round 2
// 244.005 us; speedup vs baseline: 1.4866x; 1.4866x over previous
//
#include <hip/hip_runtime.h>

#define FV 128
#define NCLIN 38
#define NPIX 36
#define BATCH 1024
#define HID 512
#define COMB 4992   // 39*128

typedef __attribute__((ext_vector_type(4))) float f32x4;
typedef __attribute__((ext_vector_type(8))) short s16x8;

// ws layout (float offsets):
//   wc       [0,        16384)     W_self + W_msg/37
//   wi       [16384,    32768)     W_self + W_msg/39
//   t_clin   [32768,   163840)     (S_img/37)@W_msg + b_g   per (b,f)
//   t_img    [163840,  294912)     (S_clin/39)@W_msg + b_g  per (b,f)
//   combined [294912,  2850816)    bf16 (1024 x 4992)  -> 10.2 MB
//   W1T      [2850816, 4128768)    bf16 (512 x 4992)   -> 5.1 MB
//   z[4]     [4128768, 6225920)    fp32 partials, 4 x (1024 x 512)
#define WS_WC   0
#define WS_WI   16384
#define WS_TC   32768
#define WS_TI   163840
#define WS_COMB 294912
#define WS_W1T  2850816
#define WS_Z    4128768

__device__ __forceinline__ unsigned short bf16_rne(float f) {
    union { float f; unsigned int u; } v; v.f = f;
    unsigned int u = v.u;
    u += 0x7fffu + ((u >> 16) & 1u);
    return (unsigned short)(u >> 16);
}

__global__ __launch_bounds__(128) void k_prep(
    const float* __restrict__ clin, const float* __restrict__ img,
    const float* __restrict__ wself, const float* __restrict__ wmsg,
    const float* __restrict__ bg, float* __restrict__ ws)
{
    const int b = blockIdx.x;
    const int f = threadIdx.x;
    if (b >= BATCH) {
        const int r = b - BATCH;
        const int idx = r * 128 + f;
        const float wm = wmsg[idx];
        const float s  = wself[idx];
        ws[WS_WC + idx] = s + wm * (1.0f / 37.0f);
        ws[WS_WI + idx] = s + wm * (1.0f / 39.0f);
        return;
    }
    __shared__ float lc[128];
    __shared__ float li[128];
    float sc = 0.f, si = 0.f;
    const float* xc = clin + (size_t)b * NCLIN * FV + f;
#pragma unroll
    for (int n = 0; n < NCLIN; ++n) sc += xc[n * FV];
    const float* xi = img + (size_t)b * NPIX * FV + f;
#pragma unroll
    for (int n = 0; n < NPIX; ++n) si += xi[n * FV];
    lc[f] = sc * (1.0f / 39.0f);
    li[f] = si * (1.0f / 37.0f);
    __syncthreads();
    const float bgv = bg[f];
    float tc = bgv, ti = bgv;
#pragma unroll 4
    for (int k = 0; k < 128; ++k) {
        const float wm = wmsg[k * 128 + f];
        tc += li[k] * wm;
        ti += lc[k] * wm;
    }
    ws[WS_TC + b * 128 + f] = tc;
    ws[WS_TI + b * 128 + f] = ti;
}

// One block per (batch, node-type). h = relu(x @ W + t); clinical h -> combined
// rows (bf16), image h -> mean (gap) -> last 128 of combined row (bf16).
__global__ __launch_bounds__(256) void k_nodes(
    const float* __restrict__ clin, const float* __restrict__ img,
    float* __restrict__ ws)
{
    const int b     = blockIdx.x;
    const int phase = blockIdx.y;
    const int NN    = phase ? NPIX : NCLIN;
    const float* x  = phase ? (img + (size_t)b * NPIX * FV)
                            : (clin + (size_t)b * NCLIN * FV);
    const float* W  = ws + (phase ? WS_WI : WS_WC);
    const float* tv = ws + (phase ? WS_TI : WS_TC) + b * 128;
    unsigned short* combined =
        (unsigned short*)(ws + WS_COMB) + (size_t)b * COMB;

    __shared__ float xl[NCLIN * 128];
    __shared__ float Wl[128 * 64];
    __shared__ float gred[16 * 64];

    const int t = threadIdx.x;
    const int cnt4 = NN * 32;
    for (int i = t; i < cnt4; i += 256)
        ((float4*)xl)[i] = ((const float4*)x)[i];

    const int g  = t >> 4;
    const int f0 = (t & 15) * 4;

    for (int fhalf = 0; fhalf < 2; ++fhalf) {
        __syncthreads();
        {
            const int fq4  = (t & 15) * 4;
            const int krow = t >> 4;
#pragma unroll
            for (int j = 0; j < 8; ++j) {
                const int k = krow + 16 * j;
                const float4 v = *(const float4*)&W[k * 128 + fhalf * 64 + fq4];
                *(float4*)&Wl[k * 64 + fq4] = v;
            }
        }
        __syncthreads();

        float acc[3][4] = {};
        for (int k0 = 0; k0 < 128; k0 += 4) {
            float4 wv0 = *(const float4*)&Wl[(k0 + 0) * 64 + f0];
            float4 wv1 = *(const float4*)&Wl[(k0 + 1) * 64 + f0];
            float4 wv2 = *(const float4*)&Wl[(k0 + 2) * 64 + f0];
            float4 wv3 = *(const float4*)&Wl[(k0 + 3) * 64 + f0];
#pragma unroll
            for (int i = 0; i < 3; ++i) {
                const int n = g + 16 * i;
                if (n < NN) {
                    const float4 xv = *(const float4*)&xl[n * 128 + k0];
                    acc[i][0] += xv.x * wv0.x + xv.y * wv1.x + xv.z * wv2.x + xv.w * wv3.x;
                    acc[i][1] += xv.x * wv0.y + xv.y * wv1.y + xv.z * wv2.y + xv.w * wv3.y;
                    acc[i][2] += xv.x * wv0.z + xv.y * wv1.z + xv.z * wv2.z + xv.w * wv3.z;
                    acc[i][3] += xv.x * wv0.w + xv.y * wv1.w + xv.z * wv2.w + xv.w * wv3.w;
                }
            }
        }

        const float t0 = tv[fhalf * 64 + f0 + 0];
        const float t1 = tv[fhalf * 64 + f0 + 1];
        const float t2 = tv[fhalf * 64 + f0 + 2];
        const float t3 = tv[fhalf * 64 + f0 + 3];

        if (phase == 0) {
#pragma unroll
            for (int i = 0; i < 3; ++i) {
                const int n = g + 16 * i;
                if (n < NN) {
                    ushort4 r;
                    r.x = bf16_rne(fmaxf(acc[i][0] + t0, 0.f));
                    r.y = bf16_rne(fmaxf(acc[i][1] + t1, 0.f));
                    r.z = bf16_rne(fmaxf(acc[i][2] + t2, 0.f));
                    r.w = bf16_rne(fmaxf(acc[i][3] + t3, 0.f));
                    *(ushort4*)&combined[n * 128 + fhalf * 64 + f0] = r;
                }
            }
        } else {
            float gp0 = 0.f, gp1 = 0.f, gp2 = 0.f, gp3 = 0.f;
#pragma unroll
            for (int i = 0; i < 3; ++i) {
                const int n = g + 16 * i;
                if (n < NN) {
                    gp0 += fmaxf(acc[i][0] + t0, 0.f);
                    gp1 += fmaxf(acc[i][1] + t1, 0.f);
                    gp2 += fmaxf(acc[i][2] + t2, 0.f);
                    gp3 += fmaxf(acc[i][3] + t3, 0.f);
                }
            }
            float4 gv = { gp0, gp1, gp2, gp3 };
            *(float4*)&gred[g * 64 + f0] = gv;
            __syncthreads();
            if (t < 64) {
                float s = 0.f;
#pragma unroll
                for (int gg = 0; gg < 16; ++gg) s += gred[gg * 64 + t];
                combined[NCLIN * 128 + fhalf * 64 + t] =
                    bf16_rne(s * (1.0f / 36.0f));
            }
        }
    }
}

// W1 (4992x512 fp32) -> W1T (512x4992 bf16), tile-transposed through LDS.
__global__ __launch_bounds__(256) void k_w1t(
    const float* __restrict__ W1, float* __restrict__ ws)
{
    unsigned short* W1T = (unsigned short*)(ws + WS_W1T);
    const int k0 = blockIdx.x * 64;
    const int n0 = blockIdx.y * 64;
    __shared__ float tile[64][65];
    const int t   = threadIdx.x;
    const int r16 = t >> 4;
    const int c4  = (t & 15) * 4;
#pragma unroll
    for (int p = 0; p < 4; ++p) {
        const int r = p * 16 + r16;
        const float4 v = *(const float4*)&W1[(size_t)(k0 + r) * HID + n0 + c4];
        tile[r][c4 + 0] = v.x; tile[r][c4 + 1] = v.y;
        tile[r][c4 + 2] = v.z; tile[r][c4 + 3] = v.w;
    }
    __syncthreads();
    const int j  = t >> 2;
    const int i0 = (t & 3) * 16;
    unsigned short tmp[16];
#pragma unroll
    for (int s = 0; s < 16; ++s) tmp[s] = bf16_rne(tile[i0 + s][j]);
    unsigned short* dst = &W1T[(size_t)(n0 + j) * COMB + k0 + i0];
    *(uint4*)&dst[0] = *(uint4*)&tmp[0];
    *(uint4*)&dst[8] = *(uint4*)&tmp[8];
}

// z[ks] += combined[:, ks*1248:(ks+1)*1248] @ W1[...]  via bf16 MFMA.
// Block tile 64m x 64n, BK=32, waves 2x2 (each 32m x 32n), grid (16,8,4).
__global__ __launch_bounds__(256) void k_gemm_mfma(float* __restrict__ ws)
{
    const unsigned short* Abase = (const unsigned short*)(ws + WS_COMB);
    const unsigned short* Bbase = (const unsigned short*)(ws + WS_W1T);
    const int m0    = blockIdx.x * 64;
    const int n0    = blockIdx.y * 64;
    const int ks    = blockIdx.z;
    const int kbase = ks * 1248;
    float* Z = ws + WS_Z + (size_t)ks * (BATCH * HID);

    __shared__ __align__(16) unsigned short As[64 * 40];  // row stride 40 (pad)
    __shared__ __align__(16) unsigned short Bs[64 * 40];  // [n][k]

    const int t    = threadIdx.x;
    const int wave = t >> 6;
    const int lane = t & 63;
    const int wm   = (wave & 1) * 32;
    const int wn   = (wave >> 1) * 32;
    const int l16  = lane & 15;
    const int q    = lane >> 4;          // 0..3 -> k offset q*8

    const int sr = t >> 2;               // staging row 0..63
    const int sc = (t & 3) * 8;          // staging k offset

    f32x4 acc00 = {}, acc01 = {}, acc10 = {}, acc11 = {};

    for (int kb = 0; kb < 1248; kb += 32) {
        __syncthreads();
        const int kk = kbase + kb + sc;
        *(uint4*)&As[sr * 40 + sc] =
            *(const uint4*)&Abase[(size_t)(m0 + sr) * COMB + kk];
        *(uint4*)&Bs[sr * 40 + sc] =
            *(const uint4*)&Bbase[(size_t)(n0 + sr) * COMB + kk];
        __syncthreads();

        const s16x8 a0 = *(const s16x8*)&As[(wm + l16) * 40 + q * 8];
        const s16x8 a1 = *(const s16x8*)&As[(wm + 16 + l16) * 40 + q * 8];
        const s16x8 b0 = *(const s16x8*)&Bs[(wn + l16) * 40 + q * 8];
        const s16x8 b1 = *(const s16x8*)&Bs[(wn + 16 + l16) * 40 + q * 8];

        acc00 = __builtin_amdgcn_mfma_f32_16x16x32_bf16(a0, b0, acc00, 0, 0, 0);
        acc01 = __builtin_amdgcn_mfma_f32_16x16x32_bf16(a0, b1, acc01, 0, 0, 0);
        acc10 = __builtin_amdgcn_mfma_f32_16x16x32_bf16(a1, b0, acc10, 0, 0, 0);
        acc11 = __builtin_amdgcn_mfma_f32_16x16x32_bf16(a1, b1, acc11, 0, 0, 0);
    }

    // C/D layout: col = lane&15, row = q*4 + reg  (m89-verified)
    const int rbase = q * 4;
#pragma unroll
    for (int r = 0; r < 4; ++r) {
        const int mr0 = m0 + wm + rbase + r;
        Z[(size_t)(mr0)      * HID + n0 + wn +      l16] = acc00[r];
        Z[(size_t)(mr0)      * HID + n0 + wn + 16 + l16] = acc01[r];
        Z[(size_t)(mr0 + 16) * HID + n0 + wn +      l16] = acc10[r];
        Z[(size_t)(mr0 + 16) * HID + n0 + wn + 16 + l16] = acc11[r];
    }
}

__global__ __launch_bounds__(64) void k_out(
    const float* __restrict__ b1, const float* __restrict__ W2,
    const float* __restrict__ b2, const float* __restrict__ ws,
    float* __restrict__ out)
{
    const int b = blockIdx.x;
    const int l = threadIdx.x;
    const float* z0 = ws + WS_Z + (size_t)b * HID;
    const float* z1 = z0 + BATCH * HID;
    const float* z2 = z1 + BATCH * HID;
    const float* z3 = z2 + BATCH * HID;
    float s = 0.f;
#pragma unroll
    for (int j = 0; j < 8; ++j) {
        const int h = l + j * 64;
        float z = z0[h] + z1[h] + z2[h] + z3[h] + b1[h];
        z = fmaxf(z, 0.f);
        s += z * W2[h];
    }
#pragma unroll
    for (int off = 32; off > 0; off >>= 1) s += __shfl_down(s, off);
    if (l == 0) out[b] = s + b2[0];
}

extern "C" void kernel_launch(void* const* d_in, const int* in_sizes, int n_in,
                              void* d_out, int out_size, void* d_ws, size_t ws_size,
                              hipStream_t stream) {
    const float* clin  = (const float*)d_in[0];
    const float* img   = (const float*)d_in[1];
    const float* wself = (const float*)d_in[2];
    const float* wmsg  = (const float*)d_in[3];
    const float* bg    = (const float*)d_in[4];
    const float* W1    = (const float*)d_in[5];
    const float* b1    = (const float*)d_in[6];
    const float* W2    = (const float*)d_in[7];
    const float* b2    = (const float*)d_in[8];
    float* ws  = (float*)d_ws;
    float* out = (float*)d_out;

    k_w1t <<<dim3(78, 8), 256, 0, stream>>>(W1, ws);
    k_prep<<<dim3(BATCH + 128), 128, 0, stream>>>(clin, img, wself, wmsg, bg, ws);
    k_nodes<<<dim3(BATCH, 2), 256, 0, stream>>>(clin, img, ws);
    k_gemm_mfma<<<dim3(16, 8, 4), 256, 0, stream>>>(ws);
    k_out<<<dim3(BATCH), 64, 0, stream>>>(b1, W2, b2, ws, out);
}

// Round 3
// 177.028 us; speedup vs baseline: 2.0491x; 1.3783x over previous
//
#include <hip/hip_runtime.h>

#define FV 128
#define NCLIN 38
#define NPIX 36
#define BATCH 1024
#define HID 512
#define COMB 4992   // 39*128

typedef __attribute__((ext_vector_type(4))) float f32x4;
typedef __attribute__((ext_vector_type(8))) short s16x8;

// ws layout (float offsets):
//   WcT bf16 [0, 8192)         (W_self + W_msg/37)^T, [n][k] k-contiguous
//   WiT bf16 [8192, 16384)     (W_self + W_msg/39)^T
//   t_clin   [16384, 147456)   (S_img/37)@W_msg + b_g   per (b,f), fp32
//   t_img    [147456, 278528)  (S_clin/39)@W_msg + b_g  per (b,f), fp32
//   combined [278528, 2834432) bf16 (1024 x 4992)
//   W1T      [2834432, 4112384) bf16 (512 x 4992)
//   z[4]     [4112384, 6209536) fp32 partials, 4 x (1024 x 512)  -> 24.8 MB total
#define WS_WCT  0
#define WS_WIT  8192
#define WS_TC   16384
#define WS_TI   147456
#define WS_COMB 278528
#define WS_W1T  2834432
#define WS_Z    4112384

__device__ __forceinline__ unsigned short bf16_rne(float f) {
    union { float f; unsigned int u; } v; v.f = f;
    unsigned int u = v.u;
    u += 0x7fffu + ((u >> 16) & 1u);
    return (unsigned short)(u >> 16);
}

__device__ __forceinline__ s16x8 load8_bf16(const float* __restrict__ p) {
    const float4 v0 = *(const float4*)p;
    const float4 v1 = *(const float4*)(p + 4);
    union { unsigned short u[8]; s16x8 v; } r;
    r.u[0] = bf16_rne(v0.x); r.u[1] = bf16_rne(v0.y);
    r.u[2] = bf16_rne(v0.z); r.u[3] = bf16_rne(v0.w);
    r.u[4] = bf16_rne(v1.x); r.u[5] = bf16_rne(v1.y);
    r.u[6] = bf16_rne(v1.z); r.u[7] = bf16_rne(v1.w);
    return r.v;
}

__global__ __launch_bounds__(128) void k_prep(
    const float* __restrict__ clin, const float* __restrict__ img,
    const float* __restrict__ wself, const float* __restrict__ wmsg,
    const float* __restrict__ bg, float* __restrict__ ws)
{
    const int b = blockIdx.x;
    const int f = threadIdx.x;
    if (b >= BATCH) {
        // weight prep: row r of W -> column r of WT (bf16)
        const int r = b - BATCH;
        const int idx = r * 128 + f;
        const float wm = wmsg[idx];
        const float s  = wself[idx];
        unsigned short* WcT = (unsigned short*)(ws + WS_WCT);
        unsigned short* WiT = (unsigned short*)(ws + WS_WIT);
        WcT[f * 128 + r] = bf16_rne(s + wm * (1.0f / 37.0f));
        WiT[f * 128 + r] = bf16_rne(s + wm * (1.0f / 39.0f));
        return;
    }
    __shared__ float lc[128];
    __shared__ float li[128];
    float sc = 0.f, si = 0.f;
    const float* xc = clin + (size_t)b * NCLIN * FV + f;
#pragma unroll
    for (int n = 0; n < NCLIN; ++n) sc += xc[n * FV];
    const float* xi = img + (size_t)b * NPIX * FV + f;
#pragma unroll
    for (int n = 0; n < NPIX; ++n) si += xi[n * FV];
    lc[f] = sc * (1.0f / 39.0f);
    li[f] = si * (1.0f / 37.0f);
    __syncthreads();
    const float bgv = bg[f];
    float tc = bgv, ti = bgv;
#pragma unroll 4
    for (int k = 0; k < 128; ++k) {
        const float wm = wmsg[k * 128 + f];
        tc += li[k] * wm;
        ti += lc[k] * wm;
    }
    ws[WS_TC + b * 128 + f] = tc;
    ws[WS_TI + b * 128 + f] = ti;
}

// MFMA node transform. Block = (batch, phase). 4 waves; wave w owns cols
// [32w, 32w+32). A-frags converted fp32->bf16 in-register from global x
// (L1-resident, 19 KB/block); B-frags from pre-transposed bf16 WT. No LDS.
__global__ __launch_bounds__(256) void k_nodes_mfma(
    const float* __restrict__ clin, const float* __restrict__ img,
    float* __restrict__ ws)
{
    const int b     = blockIdx.x;
    const int phase = blockIdx.y;
    const int NN    = phase ? NPIX : NCLIN;
    const float* x  = phase ? (img + (size_t)b * NPIX * FV)
                            : (clin + (size_t)b * NCLIN * FV);
    const unsigned short* WT =
        (const unsigned short*)(ws + (phase ? WS_WIT : WS_WCT));
    const float* tv = ws + (phase ? WS_TI : WS_TC) + b * 128;
    unsigned short* combined =
        (unsigned short*)(ws + WS_COMB) + (size_t)b * COMB;

    const int t    = threadIdx.x;
    const int wave = t >> 6;
    const int lane = t & 63;
    const int l16  = lane & 15;
    const int q    = lane >> 4;

    // clamped row indices for the 3 row-tiles (pad rows re-read row NN-1;
    // their garbage accumulators are masked in the epilogue)
    const int r0 = (l16      < NN) ? l16      : (NN - 1);
    const int r1 = (16 + l16 < NN) ? 16 + l16 : (NN - 1);
    const int r2 = (32 + l16 < NN) ? 32 + l16 : (NN - 1);
    const int n0 = wave * 32 + l16;     // col for ct=0; ct=1 is +16

    f32x4 acc[3][2] = {};

#pragma unroll
    for (int kk = 0; kk < 4; ++kk) {
        const int ko = kk * 32 + q * 8;
        const s16x8 a0 = load8_bf16(x + r0 * 128 + ko);
        const s16x8 a1 = load8_bf16(x + r1 * 128 + ko);
        const s16x8 a2 = load8_bf16(x + r2 * 128 + ko);
        const s16x8 b0 = *(const s16x8*)&WT[(n0)      * 128 + ko];
        const s16x8 b1 = *(const s16x8*)&WT[(n0 + 16) * 128 + ko];
        acc[0][0] = __builtin_amdgcn_mfma_f32_16x16x32_bf16(a0, b0, acc[0][0], 0, 0, 0);
        acc[0][1] = __builtin_amdgcn_mfma_f32_16x16x32_bf16(a0, b1, acc[0][1], 0, 0, 0);
        acc[1][0] = __builtin_amdgcn_mfma_f32_16x16x32_bf16(a1, b0, acc[1][0], 0, 0, 0);
        acc[1][1] = __builtin_amdgcn_mfma_f32_16x16x32_bf16(a1, b1, acc[1][1], 0, 0, 0);
        acc[2][0] = __builtin_amdgcn_mfma_f32_16x16x32_bf16(a2, b0, acc[2][0], 0, 0, 0);
        acc[2][1] = __builtin_amdgcn_mfma_f32_16x16x32_bf16(a2, b1, acc[2][1], 0, 0, 0);
    }

    // C/D layout: col = lane&15, row = q*4 + reg
    const float t0 = tv[wave * 32 + l16];
    const float t1 = tv[wave * 32 + 16 + l16];

    if (phase == 0) {
#pragma unroll
        for (int rt = 0; rt < 3; ++rt) {
#pragma unroll
            for (int r = 0; r < 4; ++r) {
                const int node = rt * 16 + q * 4 + r;
                if (node < NCLIN) {
                    combined[node * 128 + wave * 32 + l16] =
                        bf16_rne(fmaxf(acc[rt][0][r] + t0, 0.f));
                    combined[node * 128 + wave * 32 + 16 + l16] =
                        bf16_rne(fmaxf(acc[rt][1][r] + t1, 0.f));
                }
            }
        }
    } else {
        float g0 = 0.f, g1 = 0.f;
#pragma unroll
        for (int rt = 0; rt < 3; ++rt) {
#pragma unroll
            for (int r = 0; r < 4; ++r) {
                const int node = rt * 16 + q * 4 + r;
                if (node < NPIX) {
                    g0 += fmaxf(acc[rt][0][r] + t0, 0.f);
                    g1 += fmaxf(acc[rt][1][r] + t1, 0.f);
                }
            }
        }
        g0 += __shfl_xor(g0, 16); g0 += __shfl_xor(g0, 32);
        g1 += __shfl_xor(g1, 16); g1 += __shfl_xor(g1, 32);
        if (q == 0) {
            combined[NCLIN * 128 + wave * 32 + l16] =
                bf16_rne(g0 * (1.0f / 36.0f));
            combined[NCLIN * 128 + wave * 32 + 16 + l16] =
                bf16_rne(g1 * (1.0f / 36.0f));
        }
    }
}

// W1 (4992x512 fp32) -> W1T (512x4992 bf16), tile-transposed through LDS.
__global__ __launch_bounds__(256) void k_w1t(
    const float* __restrict__ W1, float* __restrict__ ws)
{
    unsigned short* W1T = (unsigned short*)(ws + WS_W1T);
    const int k0 = blockIdx.x * 64;
    const int n0 = blockIdx.y * 64;
    __shared__ float tile[64][65];
    const int t   = threadIdx.x;
    const int r16 = t >> 4;
    const int c4  = (t & 15) * 4;
#pragma unroll
    for (int p = 0; p < 4; ++p) {
        const int r = p * 16 + r16;
        const float4 v = *(const float4*)&W1[(size_t)(k0 + r) * HID + n0 + c4];
        tile[r][c4 + 0] = v.x; tile[r][c4 + 1] = v.y;
        tile[r][c4 + 2] = v.z; tile[r][c4 + 3] = v.w;
    }
    __syncthreads();
    const int j  = t >> 2;
    const int i0 = (t & 3) * 16;
    unsigned short tmp[16];
#pragma unroll
    for (int s = 0; s < 16; ++s) tmp[s] = bf16_rne(tile[i0 + s][j]);
    unsigned short* dst = &W1T[(size_t)(n0 + j) * COMB + k0 + i0];
    *(uint4*)&dst[0] = *(uint4*)&tmp[0];
    *(uint4*)&dst[8] = *(uint4*)&tmp[8];
}

// z[ks] = combined[:, ks*1248:(ks+1)*1248] @ W1[...]  via bf16 MFMA.
// Block tile 64m x 64n, BK=32, waves 2x2 (each 32m x 32n), grid (16,8,4).
__global__ __launch_bounds__(256) void k_gemm_mfma(float* __restrict__ ws)
{
    const unsigned short* Abase = (const unsigned short*)(ws + WS_COMB);
    const unsigned short* Bbase = (const unsigned short*)(ws + WS_W1T);
    const int m0    = blockIdx.x * 64;
    const int n0    = blockIdx.y * 64;
    const int ks    = blockIdx.z;
    const int kbase = ks * 1248;
    float* Z = ws + WS_Z + (size_t)ks * (BATCH * HID);

    __shared__ __align__(16) unsigned short As[64 * 40];
    __shared__ __align__(16) unsigned short Bs[64 * 40];

    const int t    = threadIdx.x;
    const int wave = t >> 6;
    const int lane = t & 63;
    const int wm   = (wave & 1) * 32;
    const int wn   = (wave >> 1) * 32;
    const int l16  = lane & 15;
    const int q    = lane >> 4;

    const int sr = t >> 2;
    const int sc = (t & 3) * 8;

    f32x4 acc00 = {}, acc01 = {}, acc10 = {}, acc11 = {};

    for (int kb = 0; kb < 1248; kb += 32) {
        __syncthreads();
        const int kk = kbase + kb + sc;
        *(uint4*)&As[sr * 40 + sc] =
            *(const uint4*)&Abase[(size_t)(m0 + sr) * COMB + kk];
        *(uint4*)&Bs[sr * 40 + sc] =
            *(const uint4*)&Bbase[(size_t)(n0 + sr) * COMB + kk];
        __syncthreads();

        const s16x8 a0 = *(const s16x8*)&As[(wm + l16) * 40 + q * 8];
        const s16x8 a1 = *(const s16x8*)&As[(wm + 16 + l16) * 40 + q * 8];
        const s16x8 b0 = *(const s16x8*)&Bs[(wn + l16) * 40 + q * 8];
        const s16x8 b1 = *(const s16x8*)&Bs[(wn + 16 + l16) * 40 + q * 8];

        acc00 = __builtin_amdgcn_mfma_f32_16x16x32_bf16(a0, b0, acc00, 0, 0, 0);
        acc01 = __builtin_amdgcn_mfma_f32_16x16x32_bf16(a0, b1, acc01, 0, 0, 0);
        acc10 = __builtin_amdgcn_mfma_f32_16x16x32_bf16(a1, b0, acc10, 0, 0, 0);
        acc11 = __builtin_amdgcn_mfma_f32_16x16x32_bf16(a1, b1, acc11, 0, 0, 0);
    }

    const int rbase = q * 4;
#pragma unroll
    for (int r = 0; r < 4; ++r) {
        const int mr0 = m0 + wm + rbase + r;
        Z[(size_t)(mr0)      * HID + n0 + wn +      l16] = acc00[r];
        Z[(size_t)(mr0)      * HID + n0 + wn + 16 + l16] = acc01[r];
        Z[(size_t)(mr0 + 16) * HID + n0 + wn +      l16] = acc10[r];
        Z[(size_t)(mr0 + 16) * HID + n0 + wn + 16 + l16] = acc11[r];
    }
}

__global__ __launch_bounds__(64) void k_out(
    const float* __restrict__ b1, const float* __restrict__ W2,
    const float* __restrict__ b2, const float* __restrict__ ws,
    float* __restrict__ out)
{
    const int b = blockIdx.x;
    const int l = threadIdx.x;
    const float* z0 = ws + WS_Z + (size_t)b * HID;
    const float* z1 = z0 + BATCH * HID;
    const float* z2 = z1 + BATCH * HID;
    const float* z3 = z2 + BATCH * HID;
    float s = 0.f;
#pragma unroll
    for (int j = 0; j < 8; ++j) {
        const int h = l + j * 64;
        float z = z0[h] + z1[h] + z2[h] + z3[h] + b1[h];
        z = fmaxf(z, 0.f);
        s += z * W2[h];
    }
#pragma unroll
    for (int off = 32; off > 0; off >>= 1) s += __shfl_down(s, off);
    if (l == 0) out[b] = s + b2[0];
}

extern "C" void kernel_launch(void* const* d_in, const int* in_sizes, int n_in,
                              void* d_out, int out_size, void* d_ws, size_t ws_size,
                              hipStream_t stream) {
    const float* clin  = (const float*)d_in[0];
    const float* img   = (const float*)d_in[1];
    const float* wself = (const float*)d_in[2];
    const float* wmsg  = (const float*)d_in[3];
    const float* bg    = (const float*)d_in[4];
    const float* W1    = (const float*)d_in[5];
    const float* b1    = (const float*)d_in[6];
    const float* W2    = (const float*)d_in[7];
    const float* b2    = (const float*)d_in[8];
    float* ws  = (float*)d_ws;
    float* out = (float*)d_out;

    k_w1t <<<dim3(78, 8), 256, 0, stream>>>(W1, ws);
    k_prep<<<dim3(BATCH + 128), 128, 0, stream>>>(clin, img, wself, wmsg, bg, ws);
    k_nodes_mfma<<<dim3(BATCH, 2), 256, 0, stream>>>(clin, img, ws);
    k_gemm_mfma<<<dim3(16, 8, 4), 256, 0, stream>>>(ws);
    k_out<<<dim3(BATCH), 64, 0, stream>>>(b1, W2, b2, ws, out);
}

// Round 4
// 160.013 us; speedup vs baseline: 2.2669x; 1.1063x over previous
//
#include <hip/hip_runtime.h>

#define FV 128
#define NCLIN 38
#define NPIX 36
#define NTOT 74     // NCLIN + NPIX
#define BATCH 1024
#define HID 512
#define COMB 4992   // 39*128
#define XPAD 136    // LDS row stride in ushorts: 272 B = 17*16 B (quad-bank uniform)

typedef __attribute__((ext_vector_type(4))) float f32x4;
typedef __attribute__((ext_vector_type(8))) short s16x8;

// ws layout (float offsets):
//   WcT bf16 [0, 8192)          (W_self + W_msg/37)^T, [n][k] k-contiguous
//   WiT bf16 [8192, 16384)      (W_self + W_msg/39)^T
//   combined [16384, 2572288)   bf16 (1024 x 4992)
//   W1T      [2572288, 3850240) bf16 (512 x 4992)
//   z[4]     [3850240, 5947392) fp32 partials, 4 x (1024 x 512)
#define WS_WCT  0
#define WS_WIT  8192
#define WS_COMB 16384
#define WS_W1T  2572288
#define WS_Z    3850240

__device__ __forceinline__ unsigned short bf16_rne(float f) {
    union { float f; unsigned int u; } v; v.f = f;
    unsigned int u = v.u;
    u += 0x7fffu + ((u >> 16) & 1u);
    return (unsigned short)(u >> 16);
}
__device__ __forceinline__ float bf2f(unsigned short h) {
    union { unsigned int u; float f; } v; v.u = ((unsigned int)h) << 16;
    return v.f;
}

// Static weight prep: W1 transpose->bf16 (blocks x<78) + Wc/Wi transpose (x==78).
__global__ __launch_bounds__(256) void k_static(
    const float* __restrict__ W1, const float* __restrict__ wself,
    const float* __restrict__ wmsg, float* __restrict__ ws)
{
    const int t = threadIdx.x;
    if (blockIdx.x == 78) {
        unsigned short* WcT = (unsigned short*)(ws + WS_WCT);
        unsigned short* WiT = (unsigned short*)(ws + WS_WIT);
        const int r  = blockIdx.y * 16 + (t >> 4);
        const int f0 = (t & 15) * 8;
#pragma unroll
        for (int j = 0; j < 8; ++j) {
            const int f = f0 + j;
            const int idx = r * 128 + f;
            const float wm = wmsg[idx];
            const float s  = wself[idx];
            WcT[f * 128 + r] = bf16_rne(s + wm * (1.0f / 37.0f));
            WiT[f * 128 + r] = bf16_rne(s + wm * (1.0f / 39.0f));
        }
        return;
    }
    unsigned short* W1T = (unsigned short*)(ws + WS_W1T);
    const int k0 = blockIdx.x * 64;
    const int n0 = blockIdx.y * 64;
    __shared__ float tile[64][65];
    const int r16 = t >> 4;
    const int c4  = (t & 15) * 4;
#pragma unroll
    for (int p = 0; p < 4; ++p) {
        const int r = p * 16 + r16;
        const float4 v = *(const float4*)&W1[(size_t)(k0 + r) * HID + n0 + c4];
        tile[r][c4 + 0] = v.x; tile[r][c4 + 1] = v.y;
        tile[r][c4 + 2] = v.z; tile[r][c4 + 3] = v.w;
    }
    __syncthreads();
    const int j  = t >> 2;
    const int i0 = (t & 3) * 16;
    unsigned short tmp[16];
#pragma unroll
    for (int s = 0; s < 16; ++s) tmp[s] = bf16_rne(tile[i0 + s][j]);
    unsigned short* dst = &W1T[(size_t)(n0 + j) * COMB + k0 + i0];
    *(uint4*)&dst[0] = *(uint4*)&tmp[0];
    *(uint4*)&dst[8] = *(uint4*)&tmp[8];
}

// Fused per-batch pipeline: stage x (bf16, LDS) -> feature sums -> t vectors
// (LDS) -> MFMA node transform for both phases -> combined (bf16).
__global__ __launch_bounds__(256) void k_batch(
    const float* __restrict__ clin, const float* __restrict__ img,
    const float* __restrict__ wmsg, const float* __restrict__ bg,
    float* __restrict__ ws)
{
    const int b = blockIdx.x;
    const int t = threadIdx.x;

    __shared__ __align__(16) unsigned short xl[NTOT * XPAD];  // ~20 KB
    __shared__ float lc[128];   // S_clin/39 (feeds image nodes)
    __shared__ float li[128];   // S_img/37  (feeds clinical nodes)
    __shared__ float tcv[128];  // t for clinical rows
    __shared__ float tiv[128];  // t for image rows

    // ---- stage x as bf16 ----
    const float* xc = clin + (size_t)b * NCLIN * FV;
    const float* xi = img  + (size_t)b * NPIX * FV;
    for (int i = t; i < NCLIN * 32; i += 256) {
        const int row = i >> 5, c4 = (i & 31) * 4;
        const float4 v = *(const float4*)&xc[row * 128 + c4];
        ushort4 u;
        u.x = bf16_rne(v.x); u.y = bf16_rne(v.y);
        u.z = bf16_rne(v.z); u.w = bf16_rne(v.w);
        *(ushort4*)&xl[row * XPAD + c4] = u;
    }
    for (int i = t; i < NPIX * 32; i += 256) {
        const int row = i >> 5, c4 = (i & 31) * 4;
        const float4 v = *(const float4*)&xi[row * 128 + c4];
        ushort4 u;
        u.x = bf16_rne(v.x); u.y = bf16_rne(v.y);
        u.z = bf16_rne(v.z); u.w = bf16_rne(v.w);
        *(ushort4*)&xl[(NCLIN + row) * XPAD + c4] = u;
    }
    __syncthreads();

    // ---- feature sums ----
    const int f = t & 127;
    if (t < 128) {
        float s = 0.f;
#pragma unroll
        for (int n = 0; n < NCLIN; ++n) s += bf2f(xl[n * XPAD + f]);
        lc[f] = s * (1.0f / 39.0f);
    } else {
        float s = 0.f;
#pragma unroll
        for (int n = 0; n < NPIX; ++n) s += bf2f(xl[(NCLIN + n) * XPAD + f]);
        li[f] = s * (1.0f / 37.0f);
    }
    __syncthreads();

    // ---- t vectors: tc = bg + li@W_msg (clin), ti = bg + lc@W_msg (img) ----
    {
        const float* src = (t < 128) ? li : lc;
        float acc = bg[f];
#pragma unroll 4
        for (int k = 0; k < 128; ++k) acc += src[k] * wmsg[k * 128 + f];
        if (t < 128) tcv[f] = acc; else tiv[f] = acc;
    }
    __syncthreads();

    // ---- MFMA node transform, both phases ----
    const unsigned short* WcT = (const unsigned short*)(ws + WS_WCT);
    const unsigned short* WiT = (const unsigned short*)(ws + WS_WIT);
    unsigned short* combined =
        (unsigned short*)(ws + WS_COMB) + (size_t)b * COMB;

    const int wave = t >> 6;
    const int lane = t & 63;
    const int l16  = lane & 15;
    const int q    = lane >> 4;
    const int n0   = wave * 32 + l16;

#pragma unroll
    for (int phase = 0; phase < 2; ++phase) {
        const int NN   = phase ? NPIX : NCLIN;
        const int xoff = phase ? NCLIN : 0;
        const unsigned short* WT = phase ? WiT : WcT;
        const float* tvv = phase ? tiv : tcv;

        const int r0 = xoff + ((l16      < NN) ? l16      : (NN - 1));
        const int r1 = xoff + ((16 + l16 < NN) ? 16 + l16 : (NN - 1));
        const int r2 = xoff + ((32 + l16 < NN) ? 32 + l16 : (NN - 1));

        f32x4 acc[3][2] = {};
#pragma unroll
        for (int kk = 0; kk < 4; ++kk) {
            const int ko = kk * 32 + q * 8;
            const s16x8 a0 = *(const s16x8*)&xl[r0 * XPAD + ko];
            const s16x8 a1 = *(const s16x8*)&xl[r1 * XPAD + ko];
            const s16x8 a2 = *(const s16x8*)&xl[r2 * XPAD + ko];
            const s16x8 b0 = *(const s16x8*)&WT[(n0)      * 128 + ko];
            const s16x8 b1 = *(const s16x8*)&WT[(n0 + 16) * 128 + ko];
            acc[0][0] = __builtin_amdgcn_mfma_f32_16x16x32_bf16(a0, b0, acc[0][0], 0, 0, 0);
            acc[0][1] = __builtin_amdgcn_mfma_f32_16x16x32_bf16(a0, b1, acc[0][1], 0, 0, 0);
            acc[1][0] = __builtin_amdgcn_mfma_f32_16x16x32_bf16(a1, b0, acc[1][0], 0, 0, 0);
            acc[1][1] = __builtin_amdgcn_mfma_f32_16x16x32_bf16(a1, b1, acc[1][1], 0, 0, 0);
            acc[2][0] = __builtin_amdgcn_mfma_f32_16x16x32_bf16(a2, b0, acc[2][0], 0, 0, 0);
            acc[2][1] = __builtin_amdgcn_mfma_f32_16x16x32_bf16(a2, b1, acc[2][1], 0, 0, 0);
        }

        // C/D layout: col = lane&15, row = q*4 + reg
        const float t0 = tvv[wave * 32 + l16];
        const float t1 = tvv[wave * 32 + 16 + l16];

        if (phase == 0) {
#pragma unroll
            for (int rt = 0; rt < 3; ++rt) {
#pragma unroll
                for (int r = 0; r < 4; ++r) {
                    const int node = rt * 16 + q * 4 + r;
                    if (node < NCLIN) {
                        combined[node * 128 + wave * 32 + l16] =
                            bf16_rne(fmaxf(acc[rt][0][r] + t0, 0.f));
                        combined[node * 128 + wave * 32 + 16 + l16] =
                            bf16_rne(fmaxf(acc[rt][1][r] + t1, 0.f));
                    }
                }
            }
        } else {
            float g0 = 0.f, g1 = 0.f;
#pragma unroll
            for (int rt = 0; rt < 3; ++rt) {
#pragma unroll
                for (int r = 0; r < 4; ++r) {
                    const int node = rt * 16 + q * 4 + r;
                    if (node < NPIX) {
                        g0 += fmaxf(acc[rt][0][r] + t0, 0.f);
                        g1 += fmaxf(acc[rt][1][r] + t1, 0.f);
                    }
                }
            }
            g0 += __shfl_xor(g0, 16); g0 += __shfl_xor(g0, 32);
            g1 += __shfl_xor(g1, 16); g1 += __shfl_xor(g1, 32);
            if (q == 0) {
                combined[NCLIN * 128 + wave * 32 + l16] =
                    bf16_rne(g0 * (1.0f / 36.0f));
                combined[NCLIN * 128 + wave * 32 + 16 + l16] =
                    bf16_rne(g1 * (1.0f / 36.0f));
            }
        }
    }
}

// z[ks] = combined[:, ks*1248:(ks+1)*1248] @ W1[...]  via bf16 MFMA.
// Block tile 64m x 64n, BK=32, waves 2x2 (each 32m x 32n), grid (16,8,4).
__global__ __launch_bounds__(256) void k_gemm_mfma(float* __restrict__ ws)
{
    const unsigned short* Abase = (const unsigned short*)(ws + WS_COMB);
    const unsigned short* Bbase = (const unsigned short*)(ws + WS_W1T);
    const int m0    = blockIdx.x * 64;
    const int n0    = blockIdx.y * 64;
    const int ks    = blockIdx.z;
    const int kbase = ks * 1248;
    float* Z = ws + WS_Z + (size_t)ks * (BATCH * HID);

    __shared__ __align__(16) unsigned short As[64 * 40];
    __shared__ __align__(16) unsigned short Bs[64 * 40];

    const int t    = threadIdx.x;
    const int wave = t >> 6;
    const int lane = t & 63;
    const int wm   = (wave & 1) * 32;
    const int wn   = (wave >> 1) * 32;
    const int l16  = lane & 15;
    const int q    = lane >> 4;

    const int sr = t >> 2;
    const int sc = (t & 3) * 8;

    f32x4 acc00 = {}, acc01 = {}, acc10 = {}, acc11 = {};

    for (int kb = 0; kb < 1248; kb += 32) {
        __syncthreads();
        const int kk = kbase + kb + sc;
        *(uint4*)&As[sr * 40 + sc] =
            *(const uint4*)&Abase[(size_t)(m0 + sr) * COMB + kk];
        *(uint4*)&Bs[sr * 40 + sc] =
            *(const uint4*)&Bbase[(size_t)(n0 + sr) * COMB + kk];
        __syncthreads();

        const s16x8 a0 = *(const s16x8*)&As[(wm + l16) * 40 + q * 8];
        const s16x8 a1 = *(const s16x8*)&As[(wm + 16 + l16) * 40 + q * 8];
        const s16x8 b0 = *(const s16x8*)&Bs[(wn + l16) * 40 + q * 8];
        const s16x8 b1 = *(const s16x8*)&Bs[(wn + 16 + l16) * 40 + q * 8];

        acc00 = __builtin_amdgcn_mfma_f32_16x16x32_bf16(a0, b0, acc00, 0, 0, 0);
        acc01 = __builtin_amdgcn_mfma_f32_16x16x32_bf16(a0, b1, acc01, 0, 0, 0);
        acc10 = __builtin_amdgcn_mfma_f32_16x16x32_bf16(a1, b0, acc10, 0, 0, 0);
        acc11 = __builtin_amdgcn_mfma_f32_16x16x32_bf16(a1, b1, acc11, 0, 0, 0);
    }

    const int rbase = q * 4;
#pragma unroll
    for (int r = 0; r < 4; ++r) {
        const int mr0 = m0 + wm + rbase + r;
        Z[(size_t)(mr0)      * HID + n0 + wn +      l16] = acc00[r];
        Z[(size_t)(mr0)      * HID + n0 + wn + 16 + l16] = acc01[r];
        Z[(size_t)(mr0 + 16) * HID + n0 + wn +      l16] = acc10[r];
        Z[(size_t)(mr0 + 16) * HID + n0 + wn + 16 + l16] = acc11[r];
    }
}

__global__ __launch_bounds__(64) void k_out(
    const float* __restrict__ b1, const float* __restrict__ W2,
    const float* __restrict__ b2, const float* __restrict__ ws,
    float* __restrict__ out)
{
    const int b = blockIdx.x;
    const int l = threadIdx.x;
    const float* z0 = ws + WS_Z + (size_t)b * HID;
    const float* z1 = z0 + BATCH * HID;
    const float* z2 = z1 + BATCH * HID;
    const float* z3 = z2 + BATCH * HID;
    float s = 0.f;
#pragma unroll
    for (int j = 0; j < 8; ++j) {
        const int h = l + j * 64;
        float z = z0[h] + z1[h] + z2[h] + z3[h] + b1[h];
        z = fmaxf(z, 0.f);
        s += z * W2[h];
    }
#pragma unroll
    for (int off = 32; off > 0; off >>= 1) s += __shfl_down(s, off);
    if (l == 0) out[b] = s + b2[0];
}

extern "C" void kernel_launch(void* const* d_in, const int* in_sizes, int n_in,
                              void* d_out, int out_size, void* d_ws, size_t ws_size,
                              hipStream_t stream) {
    const float* clin  = (const float*)d_in[0];
    const float* img   = (const float*)d_in[1];
    const float* wself = (const float*)d_in[2];
    const float* wmsg  = (const float*)d_in[3];
    const float* bg    = (const float*)d_in[4];
    const float* W1    = (const float*)d_in[5];
    const float* b1    = (const float*)d_in[6];
    const float* W2    = (const float*)d_in[7];
    const float* b2    = (const float*)d_in[8];
    float* ws  = (float*)d_ws;
    float* out = (float*)d_out;

    k_static<<<dim3(79, 8), 256, 0, stream>>>(W1, wself, wmsg, ws);
    k_batch <<<dim3(BATCH), 256, 0, stream>>>(clin, img, wmsg, bg, ws);
    k_gemm_mfma<<<dim3(16, 8, 4), 256, 0, stream>>>(ws);
    k_out<<<dim3(BATCH), 64, 0, stream>>>(b1, W2, b2, ws, out);
}

// Round 5
// 149.624 us; speedup vs baseline: 2.4244x; 1.0694x over previous
//
#include <hip/hip_runtime.h>

#define FV 128
#define NCLIN 38
#define NPIX 36
#define NTOT 74     // NCLIN + NPIX
#define BATCH 1024
#define HID 512
#define COMB 4992   // 39*128
#define XPAD 136    // LDS row stride in ushorts

typedef __attribute__((ext_vector_type(4))) float f32x4;
typedef __attribute__((ext_vector_type(8))) short s16x8;

// ws layout (float offsets):
//   WcT bf16 [0, 8192)           (W_self + W_msg/37)^T, [n][k]
//   WiT bf16 [8192, 16384)       (W_self + W_msg/39)^T
//   WmT bf16 [16384, 24576)      W_msg^T  (for t-vector MFMA)
//   combined [24576, 2580480)    bf16 (1024 x 4992)
//   W1T      [2580480, 3858432)  bf16 (512 x 4992)
//   z[8]     [3858432, 8052736)  fp32 partials, 8 x (1024 x 512)
#define WS_WCT  0
#define WS_WIT  8192
#define WS_WMT  16384
#define WS_COMB 24576
#define WS_W1T  2580480
#define WS_Z    3858432
#define ZSTRIDE (BATCH * HID)

__device__ __forceinline__ unsigned short bf16_rne(float f) {
    union { float f; unsigned int u; } v; v.f = f;
    unsigned int u = v.u;
    u += 0x7fffu + ((u >> 16) & 1u);
    return (unsigned short)(u >> 16);
}
__device__ __forceinline__ float bf2f(unsigned short h) {
    union { unsigned int u; float f; } v; v.u = ((unsigned int)h) << 16;
    return v.f;
}

// Static weight prep: W1 transpose->bf16 (blocks x<78) + Wc/Wi/Wm transpose (x==78).
__global__ __launch_bounds__(256) void k_static(
    const float* __restrict__ W1, const float* __restrict__ wself,
    const float* __restrict__ wmsg, float* __restrict__ ws)
{
    const int t = threadIdx.x;
    if (blockIdx.x == 78) {
        unsigned short* WcT = (unsigned short*)(ws + WS_WCT);
        unsigned short* WiT = (unsigned short*)(ws + WS_WIT);
        unsigned short* WmT = (unsigned short*)(ws + WS_WMT);
        const int r  = blockIdx.y * 16 + (t >> 4);
        const int f0 = (t & 15) * 8;
#pragma unroll
        for (int j = 0; j < 8; ++j) {
            const int f = f0 + j;
            const int idx = r * 128 + f;
            const float wm = wmsg[idx];
            const float s  = wself[idx];
            WcT[f * 128 + r] = bf16_rne(s + wm * (1.0f / 37.0f));
            WiT[f * 128 + r] = bf16_rne(s + wm * (1.0f / 39.0f));
            WmT[f * 128 + r] = bf16_rne(wm);
        }
        return;
    }
    unsigned short* W1T = (unsigned short*)(ws + WS_W1T);
    const int k0 = blockIdx.x * 64;
    const int n0 = blockIdx.y * 64;
    __shared__ float tile[64][65];
    const int r16 = t >> 4;
    const int c4  = (t & 15) * 4;
#pragma unroll
    for (int p = 0; p < 4; ++p) {
        const int r = p * 16 + r16;
        const float4 v = *(const float4*)&W1[(size_t)(k0 + r) * HID + n0 + c4];
        tile[r][c4 + 0] = v.x; tile[r][c4 + 1] = v.y;
        tile[r][c4 + 2] = v.z; tile[r][c4 + 3] = v.w;
    }
    __syncthreads();
    const int j  = t >> 2;
    const int i0 = (t & 3) * 16;
    unsigned short tmp[16];
#pragma unroll
    for (int s = 0; s < 16; ++s) tmp[s] = bf16_rne(tile[i0 + s][j]);
    unsigned short* dst = &W1T[(size_t)(n0 + j) * COMB + k0 + i0];
    *(uint4*)&dst[0] = *(uint4*)&tmp[0];
    *(uint4*)&dst[8] = *(uint4*)&tmp[8];
}

// Fused per-batch pipeline: stage x (bf16) -> feature sums -> t via MFMA ->
// MFMA node transform both phases -> combined (bf16).
__global__ __launch_bounds__(256) void k_batch(
    const float* __restrict__ clin, const float* __restrict__ img,
    const float* __restrict__ bg, float* __restrict__ ws)
{
    const int b = blockIdx.x;
    const int t = threadIdx.x;

    __shared__ __align__(16) unsigned short xl[NTOT * XPAD];
    __shared__ __align__(16) unsigned short sab[2 * 128]; // row0=S_img/37, row1=S_clin/39
    __shared__ float tcv[128];
    __shared__ float tiv[128];

    // ---- stage x as bf16 ----
    const float* xc = clin + (size_t)b * NCLIN * FV;
    const float* xi = img  + (size_t)b * NPIX * FV;
    for (int i = t; i < NCLIN * 32; i += 256) {
        const int row = i >> 5, c4 = (i & 31) * 4;
        const float4 v = *(const float4*)&xc[row * 128 + c4];
        ushort4 u;
        u.x = bf16_rne(v.x); u.y = bf16_rne(v.y);
        u.z = bf16_rne(v.z); u.w = bf16_rne(v.w);
        *(ushort4*)&xl[row * XPAD + c4] = u;
    }
    for (int i = t; i < NPIX * 32; i += 256) {
        const int row = i >> 5, c4 = (i & 31) * 4;
        const float4 v = *(const float4*)&xi[row * 128 + c4];
        ushort4 u;
        u.x = bf16_rne(v.x); u.y = bf16_rne(v.y);
        u.z = bf16_rne(v.z); u.w = bf16_rne(v.w);
        *(ushort4*)&xl[(NCLIN + row) * XPAD + c4] = u;
    }
    __syncthreads();

    // ---- feature sums -> sab (bf16) ----
    const int f = t & 127;
    if (t < 128) {
        float s = 0.f;
#pragma unroll
        for (int n = 0; n < NCLIN; ++n) s += bf2f(xl[n * XPAD + f]);
        sab[128 + f] = bf16_rne(s * (1.0f / 39.0f));
    } else {
        float s = 0.f;
#pragma unroll
        for (int n = 0; n < NPIX; ++n) s += bf2f(xl[(NCLIN + n) * XPAD + f]);
        sab[f] = bf16_rne(s * (1.0f / 37.0f));
    }
    __syncthreads();

    const int wave = t >> 6;
    const int lane = t & 63;
    const int l16  = lane & 15;
    const int q    = lane >> 4;
    const int n0   = wave * 32 + l16;

    // ---- t vectors via MFMA: T(2x128) = sab(2x128) @ W_msg ----
    {
        const unsigned short* WmT = (const unsigned short*)(ws + WS_WMT);
        const int am = (l16 < 2) ? l16 : 0;
        f32x4 ta = {}, tb = {};
#pragma unroll
        for (int kk = 0; kk < 4; ++kk) {
            const int ko = kk * 32 + q * 8;
            const s16x8 av  = *(const s16x8*)&sab[am * 128 + ko];
            const s16x8 bv0 = *(const s16x8*)&WmT[(n0)      * 128 + ko];
            const s16x8 bv1 = *(const s16x8*)&WmT[(n0 + 16) * 128 + ko];
            ta = __builtin_amdgcn_mfma_f32_16x16x32_bf16(av, bv0, ta, 0, 0, 0);
            tb = __builtin_amdgcn_mfma_f32_16x16x32_bf16(av, bv1, tb, 0, 0, 0);
        }
        // C/D: col = l16, row = q*4 + r -> rows 0,1 live in q==0, regs 0,1
        if (q == 0) {
            const int c0 = wave * 32 + l16;
            const int c1 = c0 + 16;
            const float bg0 = bg[c0], bg1 = bg[c1];
            tcv[c0] = ta[0] + bg0;  tiv[c0] = ta[1] + bg0;
            tcv[c1] = tb[0] + bg1;  tiv[c1] = tb[1] + bg1;
        }
    }
    __syncthreads();

    // ---- MFMA node transform, both phases ----
    const unsigned short* WcT = (const unsigned short*)(ws + WS_WCT);
    const unsigned short* WiT = (const unsigned short*)(ws + WS_WIT);
    unsigned short* combined =
        (unsigned short*)(ws + WS_COMB) + (size_t)b * COMB;

#pragma unroll
    for (int phase = 0; phase < 2; ++phase) {
        const int NN   = phase ? NPIX : NCLIN;
        const int xoff = phase ? NCLIN : 0;
        const unsigned short* WT = phase ? WiT : WcT;
        const float* tvv = phase ? tiv : tcv;

        const int r0 = xoff + ((l16      < NN) ? l16      : (NN - 1));
        const int r1 = xoff + ((16 + l16 < NN) ? 16 + l16 : (NN - 1));
        const int r2 = xoff + ((32 + l16 < NN) ? 32 + l16 : (NN - 1));

        f32x4 acc[3][2] = {};
#pragma unroll
        for (int kk = 0; kk < 4; ++kk) {
            const int ko = kk * 32 + q * 8;
            const s16x8 a0 = *(const s16x8*)&xl[r0 * XPAD + ko];
            const s16x8 a1 = *(const s16x8*)&xl[r1 * XPAD + ko];
            const s16x8 a2 = *(const s16x8*)&xl[r2 * XPAD + ko];
            const s16x8 b0 = *(const s16x8*)&WT[(n0)      * 128 + ko];
            const s16x8 b1 = *(const s16x8*)&WT[(n0 + 16) * 128 + ko];
            acc[0][0] = __builtin_amdgcn_mfma_f32_16x16x32_bf16(a0, b0, acc[0][0], 0, 0, 0);
            acc[0][1] = __builtin_amdgcn_mfma_f32_16x16x32_bf16(a0, b1, acc[0][1], 0, 0, 0);
            acc[1][0] = __builtin_amdgcn_mfma_f32_16x16x32_bf16(a1, b0, acc[1][0], 0, 0, 0);
            acc[1][1] = __builtin_amdgcn_mfma_f32_16x16x32_bf16(a1, b1, acc[1][1], 0, 0, 0);
            acc[2][0] = __builtin_amdgcn_mfma_f32_16x16x32_bf16(a2, b0, acc[2][0], 0, 0, 0);
            acc[2][1] = __builtin_amdgcn_mfma_f32_16x16x32_bf16(a2, b1, acc[2][1], 0, 0, 0);
        }

        const float t0 = tvv[wave * 32 + l16];
        const float t1 = tvv[wave * 32 + 16 + l16];

        if (phase == 0) {
#pragma unroll
            for (int rt = 0; rt < 3; ++rt) {
#pragma unroll
                for (int r = 0; r < 4; ++r) {
                    const int node = rt * 16 + q * 4 + r;
                    if (node < NCLIN) {
                        combined[node * 128 + wave * 32 + l16] =
                            bf16_rne(fmaxf(acc[rt][0][r] + t0, 0.f));
                        combined[node * 128 + wave * 32 + 16 + l16] =
                            bf16_rne(fmaxf(acc[rt][1][r] + t1, 0.f));
                    }
                }
            }
        } else {
            float g0 = 0.f, g1 = 0.f;
#pragma unroll
            for (int rt = 0; rt < 3; ++rt) {
#pragma unroll
                for (int r = 0; r < 4; ++r) {
                    const int node = rt * 16 + q * 4 + r;
                    if (node < NPIX) {
                        g0 += fmaxf(acc[rt][0][r] + t0, 0.f);
                        g1 += fmaxf(acc[rt][1][r] + t1, 0.f);
                    }
                }
            }
            g0 += __shfl_xor(g0, 16); g0 += __shfl_xor(g0, 32);
            g1 += __shfl_xor(g1, 16); g1 += __shfl_xor(g1, 32);
            if (q == 0) {
                combined[NCLIN * 128 + wave * 32 + l16] =
                    bf16_rne(g0 * (1.0f / 36.0f));
                combined[NCLIN * 128 + wave * 32 + 16 + l16] =
                    bf16_rne(g1 * (1.0f / 36.0f));
            }
        }
    }
}

// z[ks] = combined[:, kbase:kbase+klen] @ W1[...]  via bf16 MFMA.
// Block 64m x 128n, waves 2x2 each 32m x 64n (2a+4b reads per 8 MFMA).
// Uneven split-K=8: 4 slices of 640 + 4 slices of 608. Grid (16,4,8)=512.
__global__ __launch_bounds__(256) void k_gemm_mfma(float* __restrict__ ws)
{
    const unsigned short* Abase = (const unsigned short*)(ws + WS_COMB);
    const unsigned short* Bbase = (const unsigned short*)(ws + WS_W1T);
    const int m0    = blockIdx.x * 64;
    const int n0    = blockIdx.y * 128;
    const int ks    = blockIdx.z;
    const int kbase = (ks < 4) ? 640 * ks : 2560 + 608 * (ks - 4);
    const int kit   = (ks < 4) ? 20 : 19;
    float* Z = ws + WS_Z + (size_t)ks * ZSTRIDE;

    __shared__ __align__(16) unsigned short As[64 * 32];   // 4 KB
    __shared__ __align__(16) unsigned short Bs[128 * 32];  // 8 KB

    const int t    = threadIdx.x;
    const int wave = t >> 6;
    const int lane = t & 63;
    const int wm   = (wave & 1) * 32;
    const int wn   = (wave >> 1) * 64;
    const int l16  = lane & 15;
    const int q    = lane >> 4;

    // staging: lane i of wave w -> 16B at LDS base_w + i*16
    const int srow  = lane >> 2;         // 0..15
    const int skoff = (lane & 3) * 8;    // ushort offset in 32-k row
    const unsigned short* gA =
        Abase + (size_t)(m0 + wave * 16 + srow) * COMB + kbase + skoff;
    const unsigned short* gB0 =
        Bbase + (size_t)(n0 + wave * 32 + srow) * COMB + kbase + skoff;
    const unsigned short* gB1 = gB0 + (size_t)16 * COMB;
    unsigned short* lA  = As + wave * 512 + lane * 8;
    unsigned short* lB0 = Bs + wave * 1024 + lane * 8;
    unsigned short* lB1 = lB0 + 512;

    f32x4 acc[2][4] = {};

    for (int it = 0; it < kit; ++it) {
        const int kk = it * 32;
        __syncthreads();
        *(uint4*)lA  = *(const uint4*)(gA  + kk);
        *(uint4*)lB0 = *(const uint4*)(gB0 + kk);
        *(uint4*)lB1 = *(const uint4*)(gB1 + kk);
        __syncthreads();

        const s16x8 a0 = *(const s16x8*)&As[(wm + l16)      * 32 + q * 8];
        const s16x8 a1 = *(const s16x8*)&As[(wm + 16 + l16) * 32 + q * 8];
        const s16x8 b0 = *(const s16x8*)&Bs[(wn + l16)      * 32 + q * 8];
        const s16x8 b1 = *(const s16x8*)&Bs[(wn + 16 + l16) * 32 + q * 8];
        const s16x8 b2 = *(const s16x8*)&Bs[(wn + 32 + l16) * 32 + q * 8];
        const s16x8 b3 = *(const s16x8*)&Bs[(wn + 48 + l16) * 32 + q * 8];

        acc[0][0] = __builtin_amdgcn_mfma_f32_16x16x32_bf16(a0, b0, acc[0][0], 0, 0, 0);
        acc[0][1] = __builtin_amdgcn_mfma_f32_16x16x32_bf16(a0, b1, acc[0][1], 0, 0, 0);
        acc[0][2] = __builtin_amdgcn_mfma_f32_16x16x32_bf16(a0, b2, acc[0][2], 0, 0, 0);
        acc[0][3] = __builtin_amdgcn_mfma_f32_16x16x32_bf16(a0, b3, acc[0][3], 0, 0, 0);
        acc[1][0] = __builtin_amdgcn_mfma_f32_16x16x32_bf16(a1, b0, acc[1][0], 0, 0, 0);
        acc[1][1] = __builtin_amdgcn_mfma_f32_16x16x32_bf16(a1, b1, acc[1][1], 0, 0, 0);
        acc[1][2] = __builtin_amdgcn_mfma_f32_16x16x32_bf16(a1, b2, acc[1][2], 0, 0, 0);
        acc[1][3] = __builtin_amdgcn_mfma_f32_16x16x32_bf16(a1, b3, acc[1][3], 0, 0, 0);
    }

    // C/D: col = l16, row = q*4 + r
#pragma unroll
    for (int a = 0; a < 2; ++a) {
#pragma unroll
        for (int r = 0; r < 4; ++r) {
            const int mr = m0 + wm + 16 * a + q * 4 + r;
#pragma unroll
            for (int c = 0; c < 4; ++c) {
                Z[(size_t)mr * HID + n0 + wn + 16 * c + l16] = acc[a][c][r];
            }
        }
    }
}

__global__ __launch_bounds__(64) void k_out(
    const float* __restrict__ b1, const float* __restrict__ W2,
    const float* __restrict__ b2, const float* __restrict__ ws,
    float* __restrict__ out)
{
    const int b = blockIdx.x;
    const int l = threadIdx.x;
    const float* z = ws + WS_Z + (size_t)b * HID;
    float s = 0.f;
#pragma unroll
    for (int j = 0; j < 8; ++j) {
        const int h = l + j * 64;
        float acc = b1[h];
#pragma unroll
        for (int p = 0; p < 8; ++p) acc += z[(size_t)p * ZSTRIDE + h];
        acc = fmaxf(acc, 0.f);
        s += acc * W2[h];
    }
#pragma unroll
    for (int off = 32; off > 0; off >>= 1) s += __shfl_down(s, off);
    if (l == 0) out[b] = s + b2[0];
}

extern "C" void kernel_launch(void* const* d_in, const int* in_sizes, int n_in,
                              void* d_out, int out_size, void* d_ws, size_t ws_size,
                              hipStream_t stream) {
    const float* clin  = (const float*)d_in[0];
    const float* img   = (const float*)d_in[1];
    const float* wself = (const float*)d_in[2];
    const float* wmsg  = (const float*)d_in[3];
    const float* bg    = (const float*)d_in[4];
    const float* W1    = (const float*)d_in[5];
    const float* b1    = (const float*)d_in[6];
    const float* W2    = (const float*)d_in[7];
    const float* b2    = (const float*)d_in[8];
    float* ws  = (float*)d_ws;
    float* out = (float*)d_out;

    k_static<<<dim3(79, 8), 256, 0, stream>>>(W1, wself, wmsg, ws);
    k_batch <<<dim3(BATCH), 256, 0, stream>>>(clin, img, bg, ws);
    k_gemm_mfma<<<dim3(16, 4, 8), 256, 0, stream>>>(ws);
    k_out<<<dim3(BATCH), 64, 0, stream>>>(b1, W2, b2, ws, out);
}

// Round 6
// 147.552 us; speedup vs baseline: 2.4584x; 1.0140x over previous
//
#include <hip/hip_runtime.h>

#define FV 128
#define NCLIN 38
#define NPIX 36
#define NTOT 74     // NCLIN + NPIX
#define BATCH 1024
#define HID 512
#define COMB 4992   // 39*128
#define XPAD 136    // LDS row stride in ushorts

typedef __attribute__((ext_vector_type(4))) float f32x4;
typedef __attribute__((ext_vector_type(8))) short s16x8;

// ws layout (float offsets):
//   WcT bf16 [0, 8192)           (W_self + W_msg/37)^T, [n][k]
//   WiT bf16 [8192, 16384)       (W_self + W_msg/39)^T
//   WmT bf16 [16384, 24576)      W_msg^T  (for t-vector MFMA)
//   combined [24576, 2580480)    bf16 (1024 x 4992)
//   W1T      [2580480, 3858432)  bf16 (512 x 4992)
//   z[8]     [3858432, 8052736)  fp32 partials, 8 x (1024 x 512)
#define WS_WCT  0
#define WS_WIT  8192
#define WS_WMT  16384
#define WS_COMB 24576
#define WS_W1T  2580480
#define WS_Z    3858432
#define ZSTRIDE (BATCH * HID)

__device__ __forceinline__ unsigned short bf16_rne(float f) {
    union { float f; unsigned int u; } v; v.f = f;
    unsigned int u = v.u;
    u += 0x7fffu + ((u >> 16) & 1u);
    return (unsigned short)(u >> 16);
}
__device__ __forceinline__ float bf2f(unsigned short h) {
    union { unsigned int u; float f; } v; v.u = ((unsigned int)h) << 16;
    return v.f;
}

// Static weight prep: W1 transpose->bf16 (blocks x<78) + Wc/Wi/Wm transpose (x==78).
__global__ __launch_bounds__(256) void k_static(
    const float* __restrict__ W1, const float* __restrict__ wself,
    const float* __restrict__ wmsg, float* __restrict__ ws)
{
    const int t = threadIdx.x;
    if (blockIdx.x == 78) {
        unsigned short* WcT = (unsigned short*)(ws + WS_WCT);
        unsigned short* WiT = (unsigned short*)(ws + WS_WIT);
        unsigned short* WmT = (unsigned short*)(ws + WS_WMT);
        const int r  = blockIdx.y * 16 + (t >> 4);
        const int f0 = (t & 15) * 8;
#pragma unroll
        for (int j = 0; j < 8; ++j) {
            const int f = f0 + j;
            const int idx = r * 128 + f;
            const float wm = wmsg[idx];
            const float s  = wself[idx];
            WcT[f * 128 + r] = bf16_rne(s + wm * (1.0f / 37.0f));
            WiT[f * 128 + r] = bf16_rne(s + wm * (1.0f / 39.0f));
            WmT[f * 128 + r] = bf16_rne(wm);
        }
        return;
    }
    unsigned short* W1T = (unsigned short*)(ws + WS_W1T);
    const int k0 = blockIdx.x * 64;
    const int n0 = blockIdx.y * 64;
    __shared__ float tile[64][65];
    const int r16 = t >> 4;
    const int c4  = (t & 15) * 4;
#pragma unroll
    for (int p = 0; p < 4; ++p) {
        const int r = p * 16 + r16;
        const float4 v = *(const float4*)&W1[(size_t)(k0 + r) * HID + n0 + c4];
        tile[r][c4 + 0] = v.x; tile[r][c4 + 1] = v.y;
        tile[r][c4 + 2] = v.z; tile[r][c4 + 3] = v.w;
    }
    __syncthreads();
    const int j  = t >> 2;
    const int i0 = (t & 3) * 16;
    unsigned short tmp[16];
#pragma unroll
    for (int s = 0; s < 16; ++s) tmp[s] = bf16_rne(tile[i0 + s][j]);
    unsigned short* dst = &W1T[(size_t)(n0 + j) * COMB + k0 + i0];
    *(uint4*)&dst[0] = *(uint4*)&tmp[0];
    *(uint4*)&dst[8] = *(uint4*)&tmp[8];
}

// Fused per-batch pipeline: stage x (bf16) -> feature sums -> t via MFMA ->
// MFMA node transform both phases -> combined (bf16).
__global__ __launch_bounds__(256) void k_batch(
    const float* __restrict__ clin, const float* __restrict__ img,
    const float* __restrict__ bg, float* __restrict__ ws)
{
    const int b = blockIdx.x;
    const int t = threadIdx.x;

    __shared__ __align__(16) unsigned short xl[NTOT * XPAD];
    __shared__ __align__(16) unsigned short sab[2 * 128]; // row0=S_img/37, row1=S_clin/39
    __shared__ float tcv[128];
    __shared__ float tiv[128];

    // ---- stage x as bf16 ----
    const float* xc = clin + (size_t)b * NCLIN * FV;
    const float* xi = img  + (size_t)b * NPIX * FV;
    for (int i = t; i < NCLIN * 32; i += 256) {
        const int row = i >> 5, c4 = (i & 31) * 4;
        const float4 v = *(const float4*)&xc[row * 128 + c4];
        ushort4 u;
        u.x = bf16_rne(v.x); u.y = bf16_rne(v.y);
        u.z = bf16_rne(v.z); u.w = bf16_rne(v.w);
        *(ushort4*)&xl[row * XPAD + c4] = u;
    }
    for (int i = t; i < NPIX * 32; i += 256) {
        const int row = i >> 5, c4 = (i & 31) * 4;
        const float4 v = *(const float4*)&xi[row * 128 + c4];
        ushort4 u;
        u.x = bf16_rne(v.x); u.y = bf16_rne(v.y);
        u.z = bf16_rne(v.z); u.w = bf16_rne(v.w);
        *(ushort4*)&xl[(NCLIN + row) * XPAD + c4] = u;
    }
    __syncthreads();

    // ---- feature sums -> sab (bf16) ----
    const int f = t & 127;
    if (t < 128) {
        float s = 0.f;
#pragma unroll
        for (int n = 0; n < NCLIN; ++n) s += bf2f(xl[n * XPAD + f]);
        sab[128 + f] = bf16_rne(s * (1.0f / 39.0f));
    } else {
        float s = 0.f;
#pragma unroll
        for (int n = 0; n < NPIX; ++n) s += bf2f(xl[(NCLIN + n) * XPAD + f]);
        sab[f] = bf16_rne(s * (1.0f / 37.0f));
    }
    __syncthreads();

    const int wave = t >> 6;
    const int lane = t & 63;
    const int l16  = lane & 15;
    const int q    = lane >> 4;
    const int n0   = wave * 32 + l16;

    // ---- t vectors via MFMA: T(2x128) = sab(2x128) @ W_msg ----
    {
        const unsigned short* WmT = (const unsigned short*)(ws + WS_WMT);
        const int am = (l16 < 2) ? l16 : 0;
        f32x4 ta = {}, tb = {};
#pragma unroll
        for (int kk = 0; kk < 4; ++kk) {
            const int ko = kk * 32 + q * 8;
            const s16x8 av  = *(const s16x8*)&sab[am * 128 + ko];
            const s16x8 bv0 = *(const s16x8*)&WmT[(n0)      * 128 + ko];
            const s16x8 bv1 = *(const s16x8*)&WmT[(n0 + 16) * 128 + ko];
            ta = __builtin_amdgcn_mfma_f32_16x16x32_bf16(av, bv0, ta, 0, 0, 0);
            tb = __builtin_amdgcn_mfma_f32_16x16x32_bf16(av, bv1, tb, 0, 0, 0);
        }
        if (q == 0) {
            const int c0 = wave * 32 + l16;
            const int c1 = c0 + 16;
            const float bg0 = bg[c0], bg1 = bg[c1];
            tcv[c0] = ta[0] + bg0;  tiv[c0] = ta[1] + bg0;
            tcv[c1] = tb[0] + bg1;  tiv[c1] = tb[1] + bg1;
        }
    }
    __syncthreads();

    // ---- MFMA node transform, both phases ----
    const unsigned short* WcT = (const unsigned short*)(ws + WS_WCT);
    const unsigned short* WiT = (const unsigned short*)(ws + WS_WIT);
    unsigned short* combined =
        (unsigned short*)(ws + WS_COMB) + (size_t)b * COMB;

#pragma unroll
    for (int phase = 0; phase < 2; ++phase) {
        const int NN   = phase ? NPIX : NCLIN;
        const int xoff = phase ? NCLIN : 0;
        const unsigned short* WT = phase ? WiT : WcT;
        const float* tvv = phase ? tiv : tcv;

        const int r0 = xoff + ((l16      < NN) ? l16      : (NN - 1));
        const int r1 = xoff + ((16 + l16 < NN) ? 16 + l16 : (NN - 1));
        const int r2 = xoff + ((32 + l16 < NN) ? 32 + l16 : (NN - 1));

        f32x4 acc[3][2] = {};
#pragma unroll
        for (int kk = 0; kk < 4; ++kk) {
            const int ko = kk * 32 + q * 8;
            const s16x8 a0 = *(const s16x8*)&xl[r0 * XPAD + ko];
            const s16x8 a1 = *(const s16x8*)&xl[r1 * XPAD + ko];
            const s16x8 a2 = *(const s16x8*)&xl[r2 * XPAD + ko];
            const s16x8 b0 = *(const s16x8*)&WT[(n0)      * 128 + ko];
            const s16x8 b1 = *(const s16x8*)&WT[(n0 + 16) * 128 + ko];
            acc[0][0] = __builtin_amdgcn_mfma_f32_16x16x32_bf16(a0, b0, acc[0][0], 0, 0, 0);
            acc[0][1] = __builtin_amdgcn_mfma_f32_16x16x32_bf16(a0, b1, acc[0][1], 0, 0, 0);
            acc[1][0] = __builtin_amdgcn_mfma_f32_16x16x32_bf16(a1, b0, acc[1][0], 0, 0, 0);
            acc[1][1] = __builtin_amdgcn_mfma_f32_16x16x32_bf16(a1, b1, acc[1][1], 0, 0, 0);
            acc[2][0] = __builtin_amdgcn_mfma_f32_16x16x32_bf16(a2, b0, acc[2][0], 0, 0, 0);
            acc[2][1] = __builtin_amdgcn_mfma_f32_16x16x32_bf16(a2, b1, acc[2][1], 0, 0, 0);
        }

        const float t0 = tvv[wave * 32 + l16];
        const float t1 = tvv[wave * 32 + 16 + l16];

        if (phase == 0) {
#pragma unroll
            for (int rt = 0; rt < 3; ++rt) {
#pragma unroll
                for (int r = 0; r < 4; ++r) {
                    const int node = rt * 16 + q * 4 + r;
                    if (node < NCLIN) {
                        combined[node * 128 + wave * 32 + l16] =
                            bf16_rne(fmaxf(acc[rt][0][r] + t0, 0.f));
                        combined[node * 128 + wave * 32 + 16 + l16] =
                            bf16_rne(fmaxf(acc[rt][1][r] + t1, 0.f));
                    }
                }
            }
        } else {
            float g0 = 0.f, g1 = 0.f;
#pragma unroll
            for (int rt = 0; rt < 3; ++rt) {
#pragma unroll
                for (int r = 0; r < 4; ++r) {
                    const int node = rt * 16 + q * 4 + r;
                    if (node < NPIX) {
                        g0 += fmaxf(acc[rt][0][r] + t0, 0.f);
                        g1 += fmaxf(acc[rt][1][r] + t1, 0.f);
                    }
                }
            }
            g0 += __shfl_xor(g0, 16); g0 += __shfl_xor(g0, 32);
            g1 += __shfl_xor(g1, 16); g1 += __shfl_xor(g1, 32);
            if (q == 0) {
                combined[NCLIN * 128 + wave * 32 + l16] =
                    bf16_rne(g0 * (1.0f / 36.0f));
                combined[NCLIN * 128 + wave * 32 + 16 + l16] =
                    bf16_rne(g1 * (1.0f / 36.0f));
            }
        }
    }
}

// z[ks] = combined[:, kbase:kbase+klen] @ W1[...]  via bf16 MFMA.
// Block 64m x 128n, waves 2x2 each 32m x 64n. Ping-pong LDS double buffer,
// ONE barrier per 32-K iter. Uneven split-K=8. Grid (16,4,8)=512.
__global__ __launch_bounds__(256) void k_gemm_mfma(float* __restrict__ ws)
{
    const unsigned short* Abase = (const unsigned short*)(ws + WS_COMB);
    const unsigned short* Bbase = (const unsigned short*)(ws + WS_W1T);
    const int m0    = blockIdx.x * 64;
    const int n0    = blockIdx.y * 128;
    const int ks    = blockIdx.z;
    const int kbase = (ks < 4) ? 640 * ks : 2560 + 608 * (ks - 4);
    const int kit   = (ks < 4) ? 20 : 19;
    float* Z = ws + WS_Z + (size_t)ks * ZSTRIDE;

    // double-buffered: [buf][...]
    __shared__ __align__(16) unsigned short As[2][64 * 32];   // 2 x 4 KB
    __shared__ __align__(16) unsigned short Bs[2][128 * 32];  // 2 x 8 KB

    const int t    = threadIdx.x;
    const int wave = t >> 6;
    const int lane = t & 63;
    const int wm   = (wave & 1) * 32;
    const int wn   = (wave >> 1) * 64;
    const int l16  = lane & 15;
    const int q    = lane >> 4;

    const int srow  = lane >> 2;
    const int skoff = (lane & 3) * 8;
    const unsigned short* gA =
        Abase + (size_t)(m0 + wave * 16 + srow) * COMB + kbase + skoff;
    const unsigned short* gB0 =
        Bbase + (size_t)(n0 + wave * 32 + srow) * COMB + kbase + skoff;
    const unsigned short* gB1 = gB0 + (size_t)16 * COMB;
    const int lAo  = wave * 512 + lane * 8;
    const int lB0o = wave * 1024 + lane * 8;

    f32x4 acc[2][4] = {};

    // prologue: stage tile 0 into buf 0
    *(uint4*)&As[0][lAo]        = *(const uint4*)gA;
    *(uint4*)&Bs[0][lB0o]       = *(const uint4*)gB0;
    *(uint4*)&Bs[0][lB0o + 512] = *(const uint4*)gB1;

    int cur = 0;
    for (int it = 0; it < kit; ++it) {
        __syncthreads();   // buf[cur] staged; buf[cur^1] reads (it-1) complete
        if (it + 1 < kit) {
            const int kk = (it + 1) * 32;
            const int nxt = cur ^ 1;
            *(uint4*)&As[nxt][lAo]        = *(const uint4*)(gA  + kk);
            *(uint4*)&Bs[nxt][lB0o]       = *(const uint4*)(gB0 + kk);
            *(uint4*)&Bs[nxt][lB0o + 512] = *(const uint4*)(gB1 + kk);
        }

        const s16x8 a0 = *(const s16x8*)&As[cur][(wm + l16)      * 32 + q * 8];
        const s16x8 a1 = *(const s16x8*)&As[cur][(wm + 16 + l16) * 32 + q * 8];
        const s16x8 b0 = *(const s16x8*)&Bs[cur][(wn + l16)      * 32 + q * 8];
        const s16x8 b1 = *(const s16x8*)&Bs[cur][(wn + 16 + l16) * 32 + q * 8];
        const s16x8 b2 = *(const s16x8*)&Bs[cur][(wn + 32 + l16) * 32 + q * 8];
        const s16x8 b3 = *(const s16x8*)&Bs[cur][(wn + 48 + l16) * 32 + q * 8];

        acc[0][0] = __builtin_amdgcn_mfma_f32_16x16x32_bf16(a0, b0, acc[0][0], 0, 0, 0);
        acc[0][1] = __builtin_amdgcn_mfma_f32_16x16x32_bf16(a0, b1, acc[0][1], 0, 0, 0);
        acc[0][2] = __builtin_amdgcn_mfma_f32_16x16x32_bf16(a0, b2, acc[0][2], 0, 0, 0);
        acc[0][3] = __builtin_amdgcn_mfma_f32_16x16x32_bf16(a0, b3, acc[0][3], 0, 0, 0);
        acc[1][0] = __builtin_amdgcn_mfma_f32_16x16x32_bf16(a1, b0, acc[1][0], 0, 0, 0);
        acc[1][1] = __builtin_amdgcn_mfma_f32_16x16x32_bf16(a1, b1, acc[1][1], 0, 0, 0);
        acc[1][2] = __builtin_amdgcn_mfma_f32_16x16x32_bf16(a1, b2, acc[1][2], 0, 0, 0);
        acc[1][3] = __builtin_amdgcn_mfma_f32_16x16x32_bf16(a1, b3, acc[1][3], 0, 0, 0);

        cur ^= 1;
    }

    // C/D: col = l16, row = q*4 + r
#pragma unroll
    for (int a = 0; a < 2; ++a) {
#pragma unroll
        for (int r = 0; r < 4; ++r) {
            const int mr = m0 + wm + 16 * a + q * 4 + r;
#pragma unroll
            for (int c = 0; c < 4; ++c) {
                Z[(size_t)mr * HID + n0 + wn + 16 * c + l16] = acc[a][c][r];
            }
        }
    }
}

// 4 batches per block (one per wave).
__global__ __launch_bounds__(256) void k_out(
    const float* __restrict__ b1, const float* __restrict__ W2,
    const float* __restrict__ b2, const float* __restrict__ ws,
    float* __restrict__ out)
{
    const int b = blockIdx.x * 4 + (threadIdx.x >> 6);
    const int l = threadIdx.x & 63;
    const float* z = ws + WS_Z + (size_t)b * HID;
    float s = 0.f;
#pragma unroll
    for (int j = 0; j < 8; ++j) {
        const int h = l + j * 64;
        float acc = b1[h];
#pragma unroll
        for (int p = 0; p < 8; ++p) acc += z[(size_t)p * ZSTRIDE + h];
        acc = fmaxf(acc, 0.f);
        s += acc * W2[h];
    }
#pragma unroll
    for (int off = 32; off > 0; off >>= 1) s += __shfl_down(s, off);
    if (l == 0) out[b] = s + b2[0];
}

extern "C" void kernel_launch(void* const* d_in, const int* in_sizes, int n_in,
                              void* d_out, int out_size, void* d_ws, size_t ws_size,
                              hipStream_t stream) {
    const float* clin  = (const float*)d_in[0];
    const float* img   = (const float*)d_in[1];
    const float* wself = (const float*)d_in[2];
    const float* wmsg  = (const float*)d_in[3];
    const float* bg    = (const float*)d_in[4];
    const float* W1    = (const float*)d_in[5];
    const float* b1    = (const float*)d_in[6];
    const float* W2    = (const float*)d_in[7];
    const float* b2    = (const float*)d_in[8];
    float* ws  = (float*)d_ws;
    float* out = (float*)d_out;

    k_static<<<dim3(79, 8), 256, 0, stream>>>(W1, wself, wmsg, ws);
    k_batch <<<dim3(BATCH), 256, 0, stream>>>(clin, img, bg, ws);
    k_gemm_mfma<<<dim3(16, 4, 8), 256, 0, stream>>>(ws);
    k_out<<<dim3(BATCH / 4), 256, 0, stream>>>(b1, W2, b2, ws, out);
}